// Round 1
// baseline (453.234 us; speedup 1.0000x reference)
//
#include <hip/hip_runtime.h>

// Problem constants: B=8, N=2048, C=768, H=12, D=64
#define SEQ   2048
#define NH    12
#define HD    64
#define CDIM  768

typedef _Float16 half8  __attribute__((ext_vector_type(8)));
typedef _Float16 half4v __attribute__((ext_vector_type(4)));
typedef float    f32x4  __attribute__((ext_vector_type(4)));

__device__ __forceinline__ void load_lds16(const _Float16* g, _Float16* l) {
  __builtin_amdgcn_global_load_lds(
      (const __attribute__((address_space(1))) void*)g,
      (__attribute__((address_space(3))) void*)l, 16, 0, 0);
}

// ---------------- fp32 -> fp16 convert ----------------
__global__ void cvt_f32_f16(const float* __restrict__ in, _Float16* __restrict__ out, int n) {
  int i = (blockIdx.x * 256 + threadIdx.x) * 4;
  if (i >= n) return;
  float4 v = *(const float4*)(in + i);
  half4v o;
  o.x = (_Float16)v.x; o.y = (_Float16)v.y; o.z = (_Float16)v.z; o.w = (_Float16)v.w;
  *(half4v*)(out + i) = o;
}

// ---------------- GEMM: C[r][f] = sum_k A[r][k] * W[f][k] ----------------
// MODE 0: QKV projection epilogue -> scatter q (scaled), k to [B,H,N,D], v to [B,H,D,N]
// MODE 1: out projection epilogue -> fp32 out[r][f] + bias[f]
template <int MODE>
__global__ __launch_bounds__(256, 2) void gemm_f16(
    const _Float16* __restrict__ A, const _Float16* __restrict__ W,
    _Float16* __restrict__ qo, _Float16* __restrict__ ko, _Float16* __restrict__ vo,
    float* __restrict__ out, const float* __restrict__ bias) {
  __shared__ _Float16 As[128 * 64];
  __shared__ _Float16 Bs[128 * 64];

  const int tid  = threadIdx.x;
  const int wave = tid >> 6;
  const int lane = tid & 63;
  const int wm = wave >> 1, wn = wave & 1;
  const int l15 = lane & 15, lg = lane >> 4;
  const int rowBase = blockIdx.y * 128;
  const int colBase = blockIdx.x * 128;

  const f32x4 fzero = {0.f, 0.f, 0.f, 0.f};
  f32x4 acc[4][4];
#pragma unroll
  for (int m = 0; m < 4; ++m)
#pragma unroll
    for (int n = 0; n < 4; ++n) acc[m][n] = fzero;

  for (int kt = 0; kt < CDIM; kt += 64) {
    __syncthreads();
#pragma unroll
    for (int p = 0; p < 4; ++p) {
      int c = tid + p * 256;
      int r = c >> 3, cb = (c & 7) * 8;  // 8 chunks of 16B per 64-elem row
      load_lds16(A + (size_t)(rowBase + r) * CDIM + kt + cb, As + c * 8);
      load_lds16(W + (size_t)(colBase + r) * CDIM + kt + cb, Bs + c * 8);
    }
    __syncthreads();
#pragma unroll
    for (int ks = 0; ks < 2; ++ks) {
      half8 af[4], bf[4];
#pragma unroll
      for (int m = 0; m < 4; ++m)
        af[m] = *(const half8*)(As + (wm * 64 + m * 16 + l15) * 64 + ks * 32 + lg * 8);
#pragma unroll
      for (int n = 0; n < 4; ++n)
        bf[n] = *(const half8*)(Bs + (wn * 64 + n * 16 + l15) * 64 + ks * 32 + lg * 8);
#pragma unroll
      for (int m = 0; m < 4; ++m)
#pragma unroll
        for (int n = 0; n < 4; ++n)
          acc[m][n] = __builtin_amdgcn_mfma_f32_16x16x32_f16(af[m], bf[n], acc[m][n], 0, 0, 0);
    }
  }

  // Epilogue. C/D frag: col = lane&15, row = (lane>>4)*4 + g  [verified layout]
  if constexpr (MODE == 0) {
#pragma unroll
    for (int m = 0; m < 4; ++m) {
#pragma unroll
      for (int n = 0; n < 4; ++n) {
        int f = colBase + wn * 64 + n * 16 + l15;      // 0..2303
        int which = f / CDIM;
        int fr = f - which * CDIM;
        int h = fr >> 6, d = fr & 63;
#pragma unroll
        for (int g = 0; g < 4; ++g) {
          int r = rowBase + wm * 64 + m * 16 + lg * 4 + g;  // 0..16383
          int b = r >> 11, nn = r & 2047;
          float v = acc[m][n][g];
          size_t bh = (size_t)(b * NH + h);
          if (which == 0)      qo[(bh * SEQ + nn) * HD + d] = (_Float16)(v * 0.125f);
          else if (which == 1) ko[(bh * SEQ + nn) * HD + d] = (_Float16)v;
          else                 vo[(bh * HD + d) * SEQ + nn] = (_Float16)v;
        }
      }
    }
  } else {
#pragma unroll
    for (int m = 0; m < 4; ++m) {
#pragma unroll
      for (int n = 0; n < 4; ++n) {
        int f = colBase + wn * 64 + n * 16 + l15;
        float bv = bias[f];
#pragma unroll
        for (int g = 0; g < 4; ++g) {
          int r = rowBase + wm * 64 + m * 16 + lg * 4 + g;
          out[(size_t)r * CDIM + f] = acc[m][n][g] + bv;
        }
      }
    }
  }
}

// ---------------- Flash attention ----------------
// grid = (N/64, B*H), block = 256 (4 waves). Wave w owns 16 q-rows.
// K tile [64 keys][64 d] and V tile (transposed: [64 d][64 keys]) in swizzled LDS.
__global__ __launch_bounds__(256, 2) void attn_f16(
    const _Float16* __restrict__ qb, const _Float16* __restrict__ kb,
    const _Float16* __restrict__ vt, _Float16* __restrict__ ob) {
  __shared__ _Float16 Ks[64 * 64];
  __shared__ _Float16 Vs[64 * 64];
  __shared__ _Float16 Ps[4][16 * 72];  // per-wave P tile, padded rows (72 f16 = 144B)

  const int tid  = threadIdx.x;
  const int wave = tid >> 6;
  const int lane = tid & 63;
  const int l15 = lane & 15, lg = lane >> 4;
  const int bh = blockIdx.y;
  const int qt = blockIdx.x;

  const _Float16* qp = qb + (size_t)bh * SEQ * HD;
  const _Float16* kp = kb + (size_t)bh * SEQ * HD;
  const _Float16* vp = vt + (size_t)bh * SEQ * HD;  // [64][2048]

  // Q fragments (already scaled by 1/8): A-frag row = lane&15, k = (lane>>4)*8+j
  const int qrow = qt * 64 + wave * 16 + l15;
  const half8 qf0 = *(const half8*)(qp + (size_t)qrow * HD + lg * 8);
  const half8 qf1 = *(const half8*)(qp + (size_t)qrow * HD + 32 + lg * 8);

  const f32x4 fzero = {0.f, 0.f, 0.f, 0.f};
  f32x4 o[4];
#pragma unroll
  for (int dt = 0; dt < 4; ++dt) o[dt] = fzero;
  float mo[4], ls[4];
#pragma unroll
  for (int g = 0; g < 4; ++g) { mo[g] = -3.0e38f; ls[g] = 0.f; }

  for (int kt = 0; kt < SEQ / 64; ++kt) {
    __syncthreads();  // previous tile's LDS reads done
    // stage K (contiguous 8KB) and Vt (64 rows x 128B, stride 4KB), XOR-swizzled
#pragma unroll
    for (int p = 0; p < 2; ++p) {
      int c = tid + p * 256;
      int r = c >> 3, cb = (c & 7) * 8;
      uint4 kv = *(const uint4*)(kp + (size_t)kt * 64 * HD + c * 8);
      *(uint4*)((char*)Ks + r * 128 + ((cb * 2) ^ ((r & 7) << 4))) = kv;
      uint4 vv = *(const uint4*)(vp + (size_t)r * SEQ + kt * 64 + cb);
      *(uint4*)((char*)Vs + r * 128 + ((cb * 2) ^ ((r & 7) << 4))) = vv;
    }
    __syncthreads();

    // S = Q @ K^T : 4 key-tiles of 16, K-dim = 64 (2 mfma each)
    f32x4 s[4];
#pragma unroll
    for (int ct = 0; ct < 4; ++ct) {
      int krow = ct * 16 + l15;
      half8 kf0 = *(const half8*)((char*)Ks + krow * 128 + ((lg * 16) ^ ((krow & 7) << 4)));
      half8 kf1 = *(const half8*)((char*)Ks + krow * 128 + ((64 + lg * 16) ^ ((krow & 7) << 4)));
      s[ct] = __builtin_amdgcn_mfma_f32_16x16x32_f16(qf0, kf0, fzero, 0, 0, 0);
      s[ct] = __builtin_amdgcn_mfma_f32_16x16x32_f16(qf1, kf1, s[ct], 0, 0, 0);
    }

    // online softmax: row = lg*4+g, 16 cols per tile spread over lanes l15
#pragma unroll
    for (int g = 0; g < 4; ++g) {
      float mx = fmaxf(fmaxf(s[0][g], s[1][g]), fmaxf(s[2][g], s[3][g]));
      mx = fmaxf(mx, __shfl_xor(mx, 1));
      mx = fmaxf(mx, __shfl_xor(mx, 2));
      mx = fmaxf(mx, __shfl_xor(mx, 4));
      mx = fmaxf(mx, __shfl_xor(mx, 8));
      float mn = fmaxf(mx, mo[g]);
      float al = __expf(mo[g] - mn);
      mo[g] = mn;
      float sum = 0.f;
#pragma unroll
      for (int ct = 0; ct < 4; ++ct) {
        float pv = __expf(s[ct][g] - mn);
        s[ct][g] = pv;
        sum += pv;
      }
      sum += __shfl_xor(sum, 1);
      sum += __shfl_xor(sum, 2);
      sum += __shfl_xor(sum, 4);
      sum += __shfl_xor(sum, 8);
      ls[g] = ls[g] * al + sum;
      o[0][g] *= al; o[1][g] *= al; o[2][g] *= al; o[3][g] *= al;
    }

    // stage P (per-wave) for the PV A-operand
#pragma unroll
    for (int ct = 0; ct < 4; ++ct)
#pragma unroll
      for (int g = 0; g < 4; ++g)
        Ps[wave][(lg * 4 + g) * 72 + ct * 16 + l15] = (_Float16)s[ct][g];
    __syncthreads();  // make P visible (cross-lane via LDS)

    // O += P @ V : A-frag P[q=l15][k], B-frag from Vt_lds[d][key]
#pragma unroll
    for (int ks = 0; ks < 2; ++ks) {
      half8 pf = *(const half8*)((char*)&Ps[wave][0] + l15 * 144 + ks * 64 + lg * 16);
#pragma unroll
      for (int dt = 0; dt < 4; ++dt) {
        int vrow = dt * 16 + l15;
        half8 vf = *(const half8*)((char*)Vs + vrow * 128 + ((ks * 64 + lg * 16) ^ ((vrow & 7) << 4)));
        o[dt] = __builtin_amdgcn_mfma_f32_16x16x32_f16(pf, vf, o[dt], 0, 0, 0);
      }
    }
  }

  // epilogue: out rows n = qt*64 + wave*16 + lg*4 + g, cols d = dt*16 + l15
  const int b = bh / NH, h = bh - b * NH;
#pragma unroll
  for (int g = 0; g < 4; ++g) {
    float inv = 1.0f / ls[g];
    int n = qt * 64 + wave * 16 + lg * 4 + g;
    size_t base = ((size_t)b * SEQ + n) * CDIM + h * HD;
#pragma unroll
    for (int dt = 0; dt < 4; ++dt)
      ob[base + dt * 16 + l15] = (_Float16)(o[dt][g] * inv);
  }
}

// ---------------- launch ----------------
extern "C" void kernel_launch(void* const* d_in, const int* in_sizes, int n_in,
                              void* d_out, int out_size, void* d_ws, size_t ws_size,
                              hipStream_t stream) {
  const float* x      = (const float*)d_in[0];  // [8,2048,768]
  const float* w_qkv  = (const float*)d_in[1];  // [2304,768]
  const float* w_proj = (const float*)d_in[2];  // [768,768]
  const float* b_proj = (const float*)d_in[3];  // [768]
  float* out = (float*)d_out;                   // [8,2048,768] fp32

  const size_t XN = (size_t)8 * SEQ * CDIM;     // 12,582,912
  const size_t WQ = (size_t)3 * CDIM * CDIM;    // 1,769,472
  const size_t WP = (size_t)CDIM * CDIM;        // 589,824

  _Float16* xb    = (_Float16*)d_ws;
  _Float16* wqkvb = xb + XN;
  _Float16* wpb   = wqkvb + WQ;
  _Float16* qb    = wpb + WP;
  _Float16* kb    = qb + XN;
  _Float16* vtb   = kb + XN;
  _Float16* ob    = vtb + XN;

  cvt_f32_f16<<<(int)(XN / 1024), 256, 0, stream>>>(x, xb, (int)XN);
  cvt_f32_f16<<<(int)(WQ / 1024), 256, 0, stream>>>(w_qkv, wqkvb, (int)WQ);
  cvt_f32_f16<<<(int)(WP / 1024), 256, 0, stream>>>(w_proj, wpb, (int)WP);

  // QKV: M=16384, Nf=2304
  gemm_f16<0><<<dim3(2304 / 128, 16384 / 128), 256, 0, stream>>>(
      xb, wqkvb, qb, kb, vtb, nullptr, nullptr);

  // attention: (N/64 q-tiles, B*H)
  attn_f16<<<dim3(SEQ / 64, 8 * NH), 256, 0, stream>>>(qb, kb, vtb, ob);

  // proj: M=16384, Nf=768
  gemm_f16<1><<<dim3(CDIM / 128, 16384 / 128), 256, 0, stream>>>(
      ob, wpb, nullptr, nullptr, nullptr, out, b_proj);
}

// Round 2
// 334.344 us; speedup vs baseline: 1.3556x; 1.3556x over previous
//
#include <hip/hip_runtime.h>

// Problem constants: B=8, N=2048, C=768, H=12, D=64
#define SEQ   2048
#define NH    12
#define HD    64
#define CDIM  768

typedef _Float16 half8  __attribute__((ext_vector_type(8)));
typedef _Float16 half4v __attribute__((ext_vector_type(4)));
typedef float    f32x4  __attribute__((ext_vector_type(4)));

__device__ __forceinline__ void load_lds16(const _Float16* g, _Float16* l) {
  __builtin_amdgcn_global_load_lds(
      (const __attribute__((address_space(1))) void*)g,
      (__attribute__((address_space(3))) void*)l, 16, 0, 0);
}

// ---------------- fp32 -> fp16 convert ----------------
__global__ void cvt_f32_f16(const float* __restrict__ in, _Float16* __restrict__ out, int n) {
  int i = (blockIdx.x * 256 + threadIdx.x) * 4;
  if (i >= n) return;
  float4 v = *(const float4*)(in + i);
  half4v o;
  o.x = (_Float16)v.x; o.y = (_Float16)v.y; o.z = (_Float16)v.z; o.w = (_Float16)v.w;
  *(half4v*)(out + i) = o;
}

// ---------------- GEMM: C[r][f] = sum_k A[r][k] * W[f][k] ----------------
// MODE 0: QKV projection epilogue -> scatter q (scaled), k to [B,H,N,D], v to [B,H,D,N]
// MODE 1: out projection epilogue -> fp32 out[r][f] + bias[f]
template <int MODE>
__global__ __launch_bounds__(256, 2) void gemm_f16(
    const _Float16* __restrict__ A, const _Float16* __restrict__ W,
    _Float16* __restrict__ qo, _Float16* __restrict__ ko, _Float16* __restrict__ vo,
    float* __restrict__ out, const float* __restrict__ bias) {
  __shared__ _Float16 As[128 * 64];
  __shared__ _Float16 Bs[128 * 64];

  const int tid  = threadIdx.x;
  const int wave = tid >> 6;
  const int lane = tid & 63;
  const int wm = wave >> 1, wn = wave & 1;
  const int l15 = lane & 15, lg = lane >> 4;
  const int rowBase = blockIdx.y * 128;
  const int colBase = blockIdx.x * 128;

  const f32x4 fzero = {0.f, 0.f, 0.f, 0.f};
  f32x4 acc[4][4];
#pragma unroll
  for (int m = 0; m < 4; ++m)
#pragma unroll
    for (int n = 0; n < 4; ++n) acc[m][n] = fzero;

  for (int kt = 0; kt < CDIM; kt += 64) {
    __syncthreads();
#pragma unroll
    for (int p = 0; p < 4; ++p) {
      int c = tid + p * 256;
      int r = c >> 3, cb = (c & 7) * 8;  // 8 chunks of 16B per 64-elem row
      load_lds16(A + (size_t)(rowBase + r) * CDIM + kt + cb, As + c * 8);
      load_lds16(W + (size_t)(colBase + r) * CDIM + kt + cb, Bs + c * 8);
    }
    __syncthreads();
#pragma unroll
    for (int ks = 0; ks < 2; ++ks) {
      half8 af[4], bf[4];
#pragma unroll
      for (int m = 0; m < 4; ++m)
        af[m] = *(const half8*)(As + (wm * 64 + m * 16 + l15) * 64 + ks * 32 + lg * 8);
#pragma unroll
      for (int n = 0; n < 4; ++n)
        bf[n] = *(const half8*)(Bs + (wn * 64 + n * 16 + l15) * 64 + ks * 32 + lg * 8);
#pragma unroll
      for (int m = 0; m < 4; ++m)
#pragma unroll
        for (int n = 0; n < 4; ++n)
          acc[m][n] = __builtin_amdgcn_mfma_f32_16x16x32_f16(af[m], bf[n], acc[m][n], 0, 0, 0);
    }
  }

  // Epilogue. C/D frag: col = lane&15, row = (lane>>4)*4 + g
  if constexpr (MODE == 0) {
#pragma unroll
    for (int m = 0; m < 4; ++m) {
#pragma unroll
      for (int n = 0; n < 4; ++n) {
        int f = colBase + wn * 64 + n * 16 + l15;      // 0..2303
        int which = f / CDIM;
        int fr = f - which * CDIM;
        int h = fr >> 6, d = fr & 63;
#pragma unroll
        for (int g = 0; g < 4; ++g) {
          int r = rowBase + wm * 64 + m * 16 + lg * 4 + g;  // 0..16383
          int b = r >> 11, nn = r & 2047;
          float v = acc[m][n][g];
          size_t bh = (size_t)(b * NH + h);
          if (which == 0)      qo[(bh * SEQ + nn) * HD + d] = (_Float16)(v * 0.125f);
          else if (which == 1) ko[(bh * SEQ + nn) * HD + d] = (_Float16)v;
          else                 vo[(bh * HD + d) * SEQ + nn] = (_Float16)v;
        }
      }
    }
  } else {
#pragma unroll
    for (int m = 0; m < 4; ++m) {
#pragma unroll
      for (int n = 0; n < 4; ++n) {
        int f = colBase + wn * 64 + n * 16 + l15;
        float bv = bias[f];
#pragma unroll
        for (int g = 0; g < 4; ++g) {
          int r = rowBase + wm * 64 + m * 16 + lg * 4 + g;
          out[(size_t)r * CDIM + f] = acc[m][n][g] + bv;
        }
      }
    }
  }
}

// ---------------- Flash attention (swapped-operand QK^T, lane-local softmax) ----
// grid = (N/64, B*H), block = 256 (4 waves). Wave w owns 16 q-rows; each lane
// owns ONE query (q = lane&15) across the whole tile.
// S^T = mfma(K,Q): lane holds S[key = ct*16 + (lane>>4)*4 + g][q = lane&15].
// O^T = mfma(Vt,P): lane holds O[q = lane&15][d = dt*16 + (lane>>4)*4 + g].
__global__ __launch_bounds__(256, 4) void attn_f16(
    const _Float16* __restrict__ qb, const _Float16* __restrict__ kb,
    const _Float16* __restrict__ vt, _Float16* __restrict__ ob) {
  __shared__ _Float16 Ks[64 * 64];
  __shared__ _Float16 Vs[64 * 64];
  __shared__ _Float16 Ps[4][16 * 72];  // per-wave P tile [q][key], 72-pad rows

  const int tid  = threadIdx.x;
  const int wave = tid >> 6;
  const int lane = tid & 63;
  const int l15 = lane & 15, lg = lane >> 4;
  const int bh = blockIdx.y;
  const int qt = blockIdx.x;

  const _Float16* qp = qb + (size_t)bh * SEQ * HD;
  const _Float16* kp = kb + (size_t)bh * SEQ * HD;
  const _Float16* vp = vt + (size_t)bh * SEQ * HD;  // Vt: [64 d][2048 keys]

  // Q fragments (already scaled by 1/8): B-frag row = lane&15 = q, k = lg*8+j
  const int qrow = qt * 64 + wave * 16 + l15;
  const half8 qf0 = *(const half8*)(qp + (size_t)qrow * HD + lg * 8);
  const half8 qf1 = *(const half8*)(qp + (size_t)qrow * HD + 32 + lg * 8);

  const f32x4 fzero = {0.f, 0.f, 0.f, 0.f};
  f32x4 o[4];
#pragma unroll
  for (int dt = 0; dt < 4; ++dt) o[dt] = fzero;
  float mo = -3.0e38f, ls = 0.f;

  // T14 async staging: global->reg issue early, reg->LDS commit after barrier
  uint4 kr0, kr1, vr0, vr1;
  const int sr0 = tid >> 3, sr1 = (tid + 256) >> 3;   // tile rows
  const int scb = (tid & 7) * 8;                      // col (halfs)
  auto issue = [&](int kt) {
    kr0 = *(const uint4*)(kp + (size_t)kt * 64 * HD + (size_t)tid * 8);
    kr1 = *(const uint4*)(kp + (size_t)kt * 64 * HD + (size_t)(tid + 256) * 8);
    vr0 = *(const uint4*)(vp + (size_t)sr0 * SEQ + kt * 64 + scb);
    vr1 = *(const uint4*)(vp + (size_t)sr1 * SEQ + kt * 64 + scb);
  };
  auto commit = [&]() {
    *(uint4*)((char*)Ks + sr0 * 128 + ((scb * 2) ^ ((sr0 & 7) << 4))) = kr0;
    *(uint4*)((char*)Ks + sr1 * 128 + ((scb * 2) ^ ((sr1 & 7) << 4))) = kr1;
    *(uint4*)((char*)Vs + sr0 * 128 + ((scb * 2) ^ ((sr0 & 7) << 4))) = vr0;
    *(uint4*)((char*)Vs + sr1 * 128 + ((scb * 2) ^ ((sr1 & 7) << 4))) = vr1;
  };

  issue(0);
  commit();
  __syncthreads();

  for (int kt = 0; kt < SEQ / 64; ++kt) {
    if (kt + 1 < SEQ / 64) issue(kt + 1);  // overlap HBM with compute below

    // S^T = K @ Q^T : 4 key-subtiles of 16, inner d = 64 (2 mfma each)
    f32x4 st[4];
#pragma unroll
    for (int ct = 0; ct < 4; ++ct) {
      int krow = ct * 16 + l15;
      half8 kf0 = *(const half8*)((char*)Ks + krow * 128 + ((lg * 16) ^ ((krow & 7) << 4)));
      half8 kf1 = *(const half8*)((char*)Ks + krow * 128 + ((64 + lg * 16) ^ ((krow & 7) << 4)));
      st[ct] = __builtin_amdgcn_mfma_f32_16x16x32_f16(kf0, qf0, fzero, 0, 0, 0);
      st[ct] = __builtin_amdgcn_mfma_f32_16x16x32_f16(kf1, qf1, st[ct], 0, 0, 0);
    }

    // lane-local online softmax for query q = l15 (16 keys in-lane, x4 lanes)
    float pmax = st[0][0];
#pragma unroll
    for (int ct = 0; ct < 4; ++ct)
#pragma unroll
      for (int g = 0; g < 4; ++g) pmax = fmaxf(pmax, st[ct][g]);
    pmax = fmaxf(pmax, __shfl_xor(pmax, 16));
    pmax = fmaxf(pmax, __shfl_xor(pmax, 32));
    float mn = fmaxf(pmax, mo);
    float al = __expf(mo - mn);
    mo = mn;
    float p[4][4];
    float sum = 0.f;
#pragma unroll
    for (int ct = 0; ct < 4; ++ct)
#pragma unroll
      for (int g = 0; g < 4; ++g) {
        float pv = __expf(st[ct][g] - mn);
        p[ct][g] = pv;
        sum += pv;
      }
    sum += __shfl_xor(sum, 16);
    sum += __shfl_xor(sum, 32);
    ls = ls * al + sum;
#pragma unroll
    for (int dt = 0; dt < 4; ++dt) o[dt] *= al;

    // stage P[q][key] (per-wave, no barrier needed): 4x ds_write_b64
#pragma unroll
    for (int ct = 0; ct < 4; ++ct) {
      half4v pk;
      pk.x = (_Float16)p[ct][0]; pk.y = (_Float16)p[ct][1];
      pk.z = (_Float16)p[ct][2]; pk.w = (_Float16)p[ct][3];
      *(half4v*)(&Ps[wave][l15 * 72 + ct * 16 + lg * 4]) = pk;
    }

    // O^T += Vt @ P^T : A = Vt-frag (m=d), B = P-frag (n=q)
#pragma unroll
    for (int ks = 0; ks < 2; ++ks) {
      half8 pf = *(const half8*)((char*)&Ps[wave][0] + l15 * 144 + ks * 64 + lg * 16);
#pragma unroll
      for (int dt = 0; dt < 4; ++dt) {
        int vrow = dt * 16 + l15;
        half8 vf = *(const half8*)((char*)Vs + vrow * 128 + ((ks * 64 + lg * 16) ^ ((vrow & 7) << 4)));
        o[dt] = __builtin_amdgcn_mfma_f32_16x16x32_f16(vf, pf, o[dt], 0, 0, 0);
      }
    }

    __syncthreads();               // all waves done reading Ks/Vs for tile kt
    if (kt + 1 < SEQ / 64) commit();
    __syncthreads();
  }

  // epilogue: lane holds O[q = qrow][d = dt*16 + lg*4 + g]
  const int b = bh / NH, h = bh - b * NH;
  const float inv = 1.0f / ls;
  const size_t base = ((size_t)b * SEQ + qrow) * CDIM + h * HD;
#pragma unroll
  for (int dt = 0; dt < 4; ++dt) {
    half4v ov;
    ov.x = (_Float16)(o[dt][0] * inv); ov.y = (_Float16)(o[dt][1] * inv);
    ov.z = (_Float16)(o[dt][2] * inv); ov.w = (_Float16)(o[dt][3] * inv);
    *(half4v*)(ob + base + dt * 16 + lg * 4) = ov;
  }
}

// ---------------- launch ----------------
extern "C" void kernel_launch(void* const* d_in, const int* in_sizes, int n_in,
                              void* d_out, int out_size, void* d_ws, size_t ws_size,
                              hipStream_t stream) {
  const float* x      = (const float*)d_in[0];  // [8,2048,768]
  const float* w_qkv  = (const float*)d_in[1];  // [2304,768]
  const float* w_proj = (const float*)d_in[2];  // [768,768]
  const float* b_proj = (const float*)d_in[3];  // [768]
  float* out = (float*)d_out;                   // [8,2048,768] fp32

  const size_t XN = (size_t)8 * SEQ * CDIM;     // 12,582,912
  const size_t WQ = (size_t)3 * CDIM * CDIM;    // 1,769,472
  const size_t WP = (size_t)CDIM * CDIM;        // 589,824

  _Float16* xb    = (_Float16*)d_ws;
  _Float16* wqkvb = xb + XN;
  _Float16* wpb   = wqkvb + WQ;
  _Float16* qb    = wpb + WP;
  _Float16* kb    = qb + XN;
  _Float16* vtb   = kb + XN;
  _Float16* ob    = vtb + XN;

  cvt_f32_f16<<<(int)(XN / 1024), 256, 0, stream>>>(x, xb, (int)XN);
  cvt_f32_f16<<<(int)(WQ / 1024), 256, 0, stream>>>(w_qkv, wqkvb, (int)WQ);
  cvt_f32_f16<<<(int)(WP / 1024), 256, 0, stream>>>(w_proj, wpb, (int)WP);

  // QKV: M=16384, Nf=2304
  gemm_f16<0><<<dim3(2304 / 128, 16384 / 128), 256, 0, stream>>>(
      xb, wqkvb, qb, kb, vtb, nullptr, nullptr);

  // attention: (N/64 q-tiles, B*H)
  attn_f16<<<dim3(SEQ / 64, 8 * NH), 256, 0, stream>>>(qb, kb, vtb, ob);

  // proj: M=16384, Nf=768
  gemm_f16<1><<<dim3(CDIM / 128, 16384 / 128), 256, 0, stream>>>(
      ob, wpb, nullptr, nullptr, nullptr, out, b_proj);
}

// Round 3
// 334.326 us; speedup vs baseline: 1.3557x; 1.0001x over previous
//
#include <hip/hip_runtime.h>

// Problem constants: B=8, N=2048, C=768, H=12, D=64
#define SEQ   2048
#define NH    12
#define HD    64
#define CDIM  768

typedef _Float16 half8  __attribute__((ext_vector_type(8)));
typedef _Float16 half4v __attribute__((ext_vector_type(4)));
typedef float    f32x4  __attribute__((ext_vector_type(4)));

// 0.125 * log2(e): QK^T scores come out in log2 units -> softmax via exp2 (no mul)
#define QSCALE 0.18033688011112042f

__device__ __forceinline__ void load_lds16(const _Float16* g, _Float16* l) {
  __builtin_amdgcn_global_load_lds(
      (const __attribute__((address_space(1))) void*)g,
      (__attribute__((address_space(3))) void*)l, 16, 0, 0);
}

// ---------------- fp32 -> fp16 convert ----------------
__global__ void cvt_f32_f16(const float* __restrict__ in, _Float16* __restrict__ out, int n) {
  int i = (blockIdx.x * 256 + threadIdx.x) * 4;
  if (i >= n) return;
  float4 v = *(const float4*)(in + i);
  half4v o;
  o.x = (_Float16)v.x; o.y = (_Float16)v.y; o.z = (_Float16)v.z; o.w = (_Float16)v.w;
  *(half4v*)(out + i) = o;
}

// ---------------- GEMM: C[r][f] = sum_k A[r][k] * W[f][k] ----------------
// MODE 0: QKV projection epilogue -> scatter q (scaled by 0.125*log2e), k to
//         [B,H,N,D], v to [B,H,D,N].  MODE 1: fp32 out[r][f] + bias[f].
// GX = gridDim.x (compile-time, for cheap div/mod in the XCD swizzle).
template <int MODE, int GX>
__global__ __launch_bounds__(256, 2) void gemm_f16(
    const _Float16* __restrict__ A, const _Float16* __restrict__ W,
    _Float16* __restrict__ qo, _Float16* __restrict__ ko, _Float16* __restrict__ vo,
    float* __restrict__ out, const float* __restrict__ bias) {
  __shared__ __align__(16) _Float16 As[128 * 64];
  __shared__ __align__(16) _Float16 Bs[128 * 64];

  const int tid  = threadIdx.x;
  const int wave = tid >> 6;
  const int lane = tid & 63;
  const int wm = wave >> 1, wn = wave & 1;
  const int l15 = lane & 15, lg = lane >> 4;

  // XCD-chunked swizzle (nwg % 8 == 0 for both launches)
  const int nwg = GX * gridDim.y;
  int id = blockIdx.y * GX + blockIdx.x;
  id = (id & 7) * (nwg >> 3) + (id >> 3);
  const int rowBase = (id / GX) * 128;
  const int colBase = (id % GX) * 128;

  const f32x4 fzero = {0.f, 0.f, 0.f, 0.f};
  f32x4 acc[4][4];
#pragma unroll
  for (int m = 0; m < 4; ++m)
#pragma unroll
    for (int n = 0; n < 4; ++n) acc[m][n] = fzero;

  for (int kt = 0; kt < CDIM; kt += 64) {
    __syncthreads();
#pragma unroll
    for (int p = 0; p < 4; ++p) {
      int c = tid + p * 256;
      int r = c >> 3, cb = (c & 7) * 8;  // 8 chunks of 16B per 64-elem row
      load_lds16(A + (size_t)(rowBase + r) * CDIM + kt + cb, As + c * 8);
      load_lds16(W + (size_t)(colBase + r) * CDIM + kt + cb, Bs + c * 8);
    }
    __syncthreads();
#pragma unroll
    for (int ks = 0; ks < 2; ++ks) {
      half8 af[4], bf[4];
#pragma unroll
      for (int m = 0; m < 4; ++m)
        af[m] = *(const half8*)(As + (wm * 64 + m * 16 + l15) * 64 + ks * 32 + lg * 8);
#pragma unroll
      for (int n = 0; n < 4; ++n)
        bf[n] = *(const half8*)(Bs + (wn * 64 + n * 16 + l15) * 64 + ks * 32 + lg * 8);
#pragma unroll
      for (int m = 0; m < 4; ++m)
#pragma unroll
        for (int n = 0; n < 4; ++n)
          acc[m][n] = __builtin_amdgcn_mfma_f32_16x16x32_f16(af[m], bf[n], acc[m][n], 0, 0, 0);
    }
  }

  // Epilogue. C/D frag: col = lane&15, row = (lane>>4)*4 + g
  if constexpr (MODE == 0) {
#pragma unroll
    for (int m = 0; m < 4; ++m) {
#pragma unroll
      for (int n = 0; n < 4; ++n) {
        int f = colBase + wn * 64 + n * 16 + l15;      // 0..2303
        int which = f / CDIM;
        int fr = f - which * CDIM;
        int h = fr >> 6, d = fr & 63;
#pragma unroll
        for (int g = 0; g < 4; ++g) {
          int r = rowBase + wm * 64 + m * 16 + lg * 4 + g;  // 0..16383
          int b = r >> 11, nn = r & 2047;
          float v = acc[m][n][g];
          size_t bh = (size_t)(b * NH + h);
          if (which == 0)      qo[(bh * SEQ + nn) * HD + d] = (_Float16)(v * QSCALE);
          else if (which == 1) ko[(bh * SEQ + nn) * HD + d] = (_Float16)v;
          else                 vo[(bh * HD + d) * SEQ + nn] = (_Float16)v;
        }
      }
    }
  } else {
#pragma unroll
    for (int m = 0; m < 4; ++m) {
#pragma unroll
      for (int n = 0; n < 4; ++n) {
        int f = colBase + wn * 64 + n * 16 + l15;
        float bv = bias[f];
#pragma unroll
        for (int g = 0; g < 4; ++g) {
          int r = rowBase + wm * 64 + m * 16 + lg * 4 + g;
          out[(size_t)r * CDIM + f] = acc[m][n][g] + bv;
        }
      }
    }
  }
}

// ---------------- Flash attention ----------------
// grid = (N/128, B*H), block = 256 (4 waves). Wave owns 32 q-rows (2 blocks of
// 16); each lane owns 2 queries (q = qb2*16 + lane&15).
// S^T = mfma16x16x32(K,Q): lane holds S[key=ct*16+lg*4+g][q=l15] -> this IS the
// B-frag of mfma_f32_16x16x16f16, so P feeds PV from registers (no LDS).
// PV: O^T = mfma16x16x16(V,P): A-frag = Vt[d=dt*16+l15][key=ct*16+lg*4+j] as
// ds_read_b64 from a slot-swizzled [d][key] LDS tile.
// K/V staged via global_load_lds with pre-swizzled GLOBAL source (linear LDS
// dest), double-buffered, ONE barrier per tile.
__global__ __launch_bounds__(256, 4) void attn_f16(
    const _Float16* __restrict__ qb, const _Float16* __restrict__ kb,
    const _Float16* __restrict__ vt, _Float16* __restrict__ ob) {
  __shared__ __align__(16) _Float16 Ks[2][64 * 64];
  __shared__ __align__(16) _Float16 Vs[2][64 * 64];

  const int tid  = threadIdx.x;
  const int wave = tid >> 6;
  const int lane = tid & 63;
  const int l15 = lane & 15, lg = lane >> 4;
  const int bh = blockIdx.y;
  const int qt = blockIdx.x;

  const _Float16* qp = qb + (size_t)bh * SEQ * HD;
  const _Float16* kp = kb + (size_t)bh * SEQ * HD;
  const _Float16* vp = vt + (size_t)bh * SEQ * HD;  // Vt: [64 d][2048 keys]

  // Q fragments (pre-scaled by 0.125*log2e): B-frag n = l15 = q, k = lg*8+j
  half8 qf[2][2];
#pragma unroll
  for (int qb2 = 0; qb2 < 2; ++qb2) {
    int qrow = qt * 128 + wave * 32 + qb2 * 16 + l15;
    qf[qb2][0] = *(const half8*)(qp + (size_t)qrow * HD + lg * 8);
    qf[qb2][1] = *(const half8*)(qp + (size_t)qrow * HD + 32 + lg * 8);
  }

  const f32x4 fzero = {0.f, 0.f, 0.f, 0.f};
  f32x4 o[2][4];
#pragma unroll
  for (int qb2 = 0; qb2 < 2; ++qb2)
#pragma unroll
    for (int dt = 0; dt < 4; ++dt) o[qb2][dt] = fzero;
  float mo[2] = {-3.0e38f, -3.0e38f}, ls[2] = {0.f, 0.f};

  // Staging: 4 global_load_lds per thread (2 K + 2 V), 16B each, linear LDS
  // dest; swizzles are applied by permuting the GLOBAL source address.
  //  K content at (row r, byte x): global col byte x ^ ((r&7)<<4)
  //  V content at (row d, slot8 s): global key granule c4 = s ^ (d&14)
  auto stage = [&](int buf, int kt) {
#pragma unroll
    for (int p = 0; p < 2; ++p) {
      int c = tid + p * 256;         // 0..511
      int r = c >> 3;                // K key-row / V d-row
      int x = (c & 7) * 16;          // dest byte offset within 128B row
      const _Float16* kg = kp + (size_t)(kt * 64 + r) * HD + ((x ^ ((r & 7) << 4)) >> 1);
      load_lds16(kg, &Ks[buf][0] + r * 64 + (x >> 1));
      int s8 = x >> 3;               // even slot index
      int c4 = s8 ^ (r & 14);
      const _Float16* vg = vp + (size_t)r * SEQ + kt * 64 + c4 * 4;
      load_lds16(vg, &Vs[buf][0] + r * 64 + s8 * 4);
    }
  };

  stage(0, 0);
  __syncthreads();
  int buf = 0;

  for (int kt = 0; kt < SEQ / 64; ++kt) {
    if (kt + 1 < SEQ / 64) stage(buf ^ 1, kt + 1);  // DMA in flight over compute

    // ---- S^T = K @ Q^T : 4 key-subtiles x 2 q-subtiles, d-depth 64
    f32x4 st[2][4];
    __builtin_amdgcn_s_setprio(1);
#pragma unroll
    for (int ct = 0; ct < 4; ++ct) {
      int krow = ct * 16 + l15;
      const char* kbase = (const char*)&Ks[buf][0] + krow * 128;
      half8 kf0 = *(const half8*)(kbase + ((lg * 16) ^ ((krow & 7) << 4)));
      half8 kf1 = *(const half8*)(kbase + ((64 + lg * 16) ^ ((krow & 7) << 4)));
#pragma unroll
      for (int qb2 = 0; qb2 < 2; ++qb2) {
        st[qb2][ct] = __builtin_amdgcn_mfma_f32_16x16x32_f16(kf0, qf[qb2][0], fzero, 0, 0, 0);
        st[qb2][ct] = __builtin_amdgcn_mfma_f32_16x16x32_f16(kf1, qf[qb2][1], st[qb2][ct], 0, 0, 0);
      }
    }
    __builtin_amdgcn_s_setprio(0);

    // ---- lane-local online softmax (log2 domain), P packed to f16 in-register
    half4v pf[2][4];
#pragma unroll
    for (int qb2 = 0; qb2 < 2; ++qb2) {
      float pmax = st[qb2][0][0];
#pragma unroll
      for (int ct = 0; ct < 4; ++ct)
#pragma unroll
        for (int g = 0; g < 4; ++g) pmax = fmaxf(pmax, st[qb2][ct][g]);
      pmax = fmaxf(pmax, __shfl_xor(pmax, 16));
      pmax = fmaxf(pmax, __shfl_xor(pmax, 32));
      if (!__all(pmax <= mo[qb2] + 8.0f)) {   // T13 defer-max (rarely taken)
        float mn = fmaxf(pmax, mo[qb2]);
        float al = exp2f(mo[qb2] - mn);
        ls[qb2] *= al;
#pragma unroll
        for (int dt = 0; dt < 4; ++dt) o[qb2][dt] *= al;
        mo[qb2] = mn;
      }
      float sum = 0.f;
#pragma unroll
      for (int ct = 0; ct < 4; ++ct) {
#pragma unroll
        for (int g = 0; g < 4; ++g) {
          float pv = exp2f(st[qb2][ct][g] - mo[qb2]);  // bounded by 2^8
          sum += pv;
          pf[qb2][ct][g] = (_Float16)pv;
        }
      }
      sum += __shfl_xor(sum, 16);
      sum += __shfl_xor(sum, 32);
      ls[qb2] += sum;
    }

    // ---- O^T += V @ P : A = Vt b64 frags (shared across qb2), B = P in-reg
    __builtin_amdgcn_s_setprio(1);
#pragma unroll
    for (int ct = 0; ct < 4; ++ct) {
#pragma unroll
      for (int dt = 0; dt < 4; ++dt) {
        int d = dt * 16 + l15;
        half4v vf = *(const half4v*)((const char*)&Vs[buf][0] + d * 128 +
                                     (((ct * 4 + lg) ^ (d & 14)) * 8));
        o[0][dt] = __builtin_amdgcn_mfma_f32_16x16x16f16(vf, pf[0][ct], o[0][dt], 0, 0, 0);
        o[1][dt] = __builtin_amdgcn_mfma_f32_16x16x16f16(vf, pf[1][ct], o[1][dt], 0, 0, 0);
      }
    }
    __builtin_amdgcn_s_setprio(0);

    __syncthreads();  // reads of buf done everywhere; buf^1 committed (vmcnt drain)
    buf ^= 1;
  }

  // epilogue: lane holds O[q = qb2*16+l15][d = dt*16 + lg*4 + g]
  const int b = bh / NH, h = bh - b * NH;
#pragma unroll
  for (int qb2 = 0; qb2 < 2; ++qb2) {
    const float inv = 1.0f / ls[qb2];
    int q = qt * 128 + wave * 32 + qb2 * 16 + l15;
    size_t base = ((size_t)b * SEQ + q) * CDIM + h * HD;
#pragma unroll
    for (int dt = 0; dt < 4; ++dt) {
      half4v ov;
      ov.x = (_Float16)(o[qb2][dt][0] * inv); ov.y = (_Float16)(o[qb2][dt][1] * inv);
      ov.z = (_Float16)(o[qb2][dt][2] * inv); ov.w = (_Float16)(o[qb2][dt][3] * inv);
      *(half4v*)(ob + base + dt * 16 + lg * 4) = ov;
    }
  }
}

// ---------------- launch ----------------
extern "C" void kernel_launch(void* const* d_in, const int* in_sizes, int n_in,
                              void* d_out, int out_size, void* d_ws, size_t ws_size,
                              hipStream_t stream) {
  const float* x      = (const float*)d_in[0];  // [8,2048,768]
  const float* w_qkv  = (const float*)d_in[1];  // [2304,768]
  const float* w_proj = (const float*)d_in[2];  // [768,768]
  const float* b_proj = (const float*)d_in[3];  // [768]
  float* out = (float*)d_out;                   // [8,2048,768] fp32

  const size_t XN = (size_t)8 * SEQ * CDIM;     // 12,582,912
  const size_t WQ = (size_t)3 * CDIM * CDIM;    // 1,769,472
  const size_t WP = (size_t)CDIM * CDIM;        // 589,824

  _Float16* xb    = (_Float16*)d_ws;
  _Float16* wqkvb = xb + XN;
  _Float16* wpb   = wqkvb + WQ;
  _Float16* qb    = wpb + WP;
  _Float16* kb    = qb + XN;
  _Float16* vtb   = kb + XN;
  _Float16* ob    = vtb + XN;

  cvt_f32_f16<<<(int)(XN / 1024), 256, 0, stream>>>(x, xb, (int)XN);
  cvt_f32_f16<<<(int)(WQ / 1024), 256, 0, stream>>>(w_qkv, wqkvb, (int)WQ);
  cvt_f32_f16<<<(int)(WP / 1024), 256, 0, stream>>>(w_proj, wpb, (int)WP);

  // QKV: M=16384, Nf=2304  (grid 18x128 = 2304 blocks, %8==0)
  gemm_f16<0, 18><<<dim3(18, 128), 256, 0, stream>>>(
      xb, wqkvb, qb, kb, vtb, nullptr, nullptr);

  // attention: (N/128 q-tiles, B*H)
  attn_f16<<<dim3(SEQ / 128, 8 * NH), 256, 0, stream>>>(qb, kb, vtb, ob);

  // proj: M=16384, Nf=768  (grid 6x128 = 768 blocks, %8==0)
  gemm_f16<1, 6><<<dim3(6, 128), 256, 0, stream>>>(
      ob, wpb, nullptr, nullptr, nullptr, out, b_proj);
}